// Round 7
// baseline (41.901 us; speedup 1.0000x reference)
//
#include <hip/hip_runtime.h>
#include <math.h>

#define MAP_SIZE 256
#define KV 64
#define HPX (1.0f / 256.0f)
#define TK 288539.0083f            // 2 * 100000 * log2(e)

__global__ __launch_bounds__(256, 8) void cdm_pass1(
    const float* __restrict__ contour,   // (bn, KV, 2)
    float* __restrict__ out,             // (bn, 256, 256) unnormalized prod
    unsigned int* __restrict__ gmax)
{
    __shared__ float4 cv4[KV / 2];       // vertex pairs (2j, 2j+1)
    const int blocksPerImg = (MAP_SIZE * MAP_SIZE) / 256;  // 256
    const int bn  = blockIdx.x / blocksPerImg;
    const int pix = (blockIdx.x % blocksPerImg) * 256 + threadIdx.x;

    if (threadIdx.x < KV / 2)
        cv4[threadIdx.x] = ((const float4*)contour)[bn * (KV / 2) + threadIdx.x];
    __syncthreads();

    const float mx = (float)(pix >> 8) * HPX;
    const float my = (float)(pix & 255) * HPX;

    const float4 q0 = cv4[0];
    float ax = q0.x - mx;    // carried: A - m
    float ay = q0.y - my;

    float mindd = 1e30f;
    float corr  = 0.0f;      // tanh-vs-sign deviation sum (only ~0 near edges)
    float wnf   = 0.0f;      // winding number (float accumulate)
    bool  pgt   = ay > 0.0f;

    // Branch-free fused edge pass:
    // resize = |W + sum sg * d2 * [dot<0]|, d2 = 1/(exp(2K|cr|)+1)
    // (pi from angle~=pi cancels 1/2pi; exp2->inf->rcp->0 kills out-of-band)
    auto edge = [&](float bx, float by) {
        const float rx = bx - mx;
        const float ry = by - my;
        const float rr = fmaf(rx, rx, ry * ry);
        mindd = fminf(mindd, rr);
        const float cr = fmaf(ay, rx, -ax * ry);
        const bool ngt  = ry > 0.0f;
        const bool crlt = cr < 0.0f;
        wnf += ((!pgt) & ngt & crlt) ? 1.0f : 0.0f;
        wnf -= ((pgt) & (!ngt) & (!crlt)) ? 1.0f : 0.0f;
        const float e   = __builtin_amdgcn_exp2f(__builtin_fabsf(cr) * TK);
        const float d2  = __builtin_amdgcn_rcpf(e + 1.0f);
        const float dot = fmaf(ax, rx, ay * ry);
        const float t   = (dot < 0.0f) ? d2 : 0.0f;
        corr += crlt ? -t : t;
        ax = rx; ay = ry; pgt = ngt;
    };

    edge(q0.z, q0.w);                   // v0 -> v1
    #pragma unroll 4
    for (int jj = 1; jj < KV / 2; ++jj) {
        const float4 t = cv4[jj];
        edge(t.x, t.y);                 // -> v(2jj)
        edge(t.z, t.w);                 // -> v(2jj+1)
    }
    edge(q0.x, q0.y);                   // wrap v63 -> v0

    const float resize = __builtin_fabsf(wnf + corr);
    const float pv = resize * __builtin_amdgcn_sqrtf(mindd);
    out[bn * (MAP_SIZE * MAP_SIZE) + pix] = pv;

    // block max reduction (pv >= 0 -> float bits compare as uint)
    float m = pv;
    #pragma unroll
    for (int off = 32; off > 0; off >>= 1)
        m = fmaxf(m, __shfl_xor(m, off));

    __shared__ float wmax[4];
    const int lane = threadIdx.x & 63;
    const int wid  = threadIdx.x >> 6;
    if (lane == 0) wmax[wid] = m;
    __syncthreads();
    if (threadIdx.x == 0) {
        const float bm = fmaxf(fmaxf(wmax[0], wmax[1]), fmaxf(wmax[2], wmax[3]));
        atomicMax(gmax, __float_as_uint(bm));
    }
}

__global__ __launch_bounds__(256) void cdm_pass2(
    float4* __restrict__ out, const unsigned int* __restrict__ gmax, int n4)
{
    const float inv = 1.0f / __uint_as_float(*gmax);
    const int i = blockIdx.x * 256 + threadIdx.x;
    if (i < n4) {
        float4 v = out[i];
        v.x *= inv; v.y *= inv; v.z *= inv; v.w *= inv;
        out[i] = v;
    }
}

extern "C" void kernel_launch(void* const* d_in, const int* in_sizes, int n_in,
                              void* d_out, int out_size, void* d_ws, size_t ws_size,
                              hipStream_t stream) {
    const float* contour = (const float*)d_in[0];
    float* out = (float*)d_out;
    unsigned int* gmax = (unsigned int*)d_ws;

    const int bn = in_sizes[0] / (KV * 2);            // 8
    const int npix = bn * MAP_SIZE * MAP_SIZE;        // 524288 == out_size

    hipMemsetAsync(gmax, 0, sizeof(unsigned int), stream);

    const int blocksPerImg = (MAP_SIZE * MAP_SIZE) / 256;
    cdm_pass1<<<bn * blocksPerImg, 256, 0, stream>>>(contour, out, gmax);

    const int n4 = npix / 4;
    cdm_pass2<<<(n4 + 255) / 256, 256, 0, stream>>>((float4*)out, gmax, n4);
}

// Round 8
// 31.160 us; speedup vs baseline: 1.3447x; 1.3447x over previous
//
#include <hip/hip_runtime.h>
#include <math.h>

#define MAP_SIZE 256
#define KV 64
#define PPT 4                      // pixels per thread: consecutive y
#define HPX (1.0f / 256.0f)
#define TK 288539.0083f            // 2 * 100000 * log2(e)

__global__ __launch_bounds__(256) void cdm_pass1(
    const float* __restrict__ contour,   // (bn, KV, 2)
    float* __restrict__ out,             // (bn, 256, 256) unnormalized prod
    float* __restrict__ bmax)            // per-block max (no atomics)
{
    __shared__ float4 cv4[KV / 2];       // vertex pairs (2j, 2j+1)
    const int blocksPerImg = (MAP_SIZE * MAP_SIZE) / (256 * PPT);  // 64
    const int bn = blockIdx.x / blocksPerImg;
    const int p0 = (blockIdx.x % blocksPerImg) * (256 * PPT) + threadIdx.x * PPT;

    if (threadIdx.x < KV / 2)
        cv4[threadIdx.x] = ((const float4*)contour)[bn * (KV / 2) + threadIdx.x];
    __syncthreads();

    const float mx  = (float)(p0 >> 8) * HPX;   // shared by the 4 pixels
    const float my0 = (float)(p0 & 255) * HPX;  // pixel i at my0 + i*HPX

    const float4 q0 = cv4[0];
    float ax  = q0.x - mx;     // carried: A - m (x shared, y for px0)
    float ay0 = q0.y - my0;

    float mindd[PPT], corr[PPT], wnf[PPT];
    bool  pgt[PPT];
    #pragma unroll
    for (int i = 0; i < PPT; ++i) {
        mindd[i] = 1e30f; corr[i] = 0.0f; wnf[i] = 0.0f;
        pgt[i] = (ay0 - (float)i * HPX) > 0.0f;
    }

    // Branch-free fused edge pass (per pixel):
    //   resize = |W + sum sg*d2*[dot<0]|,  d2 = 1/(exp(2K|cr|)+1)
    //   (angle~=pi in-band cancels 1/2pi; exp2->inf->rcp->0 kills out-of-band)
    auto edge = [&](float bx, float by) {
        const float rx  = bx - mx;                   // shared
        const float ry0 = by - my0;                  // shared
        const float rxx = rx * rx;                   // shared
        const float ex  = rx - ax;                   // Bx - Ax   (shared)
        const float cr0 = fmaf(ay0, rx, -ax * ry0);  // cross px0 (shared)
        const float sdx = ax * rx;                   // dot x-part (shared)
        #pragma unroll
        for (int i = 0; i < PPT; ++i) {
            const float iH = (float)i * HPX;
            const float ry = ry0 - iH;
            const float ay = ay0 - iH;
            const float rr = fmaf(ry, ry, rxx);
            mindd[i] = fminf(mindd[i], rr);
            const float cr = fmaf(-iH, ex, cr0);
            const bool ngt  = ry > 0.0f;
            const bool crlt = cr < 0.0f;
            wnf[i] += ((!pgt[i]) & ngt & crlt) ? 1.0f : 0.0f;
            wnf[i] -= ((pgt[i]) & (!ngt) & (!crlt)) ? 1.0f : 0.0f;
            const float e   = __builtin_amdgcn_exp2f(__builtin_fabsf(cr) * TK);
            const float d2  = __builtin_amdgcn_rcpf(e + 1.0f);
            const float dot = fmaf(ay, ry, sdx);
            const float t   = (dot < 0.0f) ? d2 : 0.0f;
            corr[i] += crlt ? -t : t;
            pgt[i] = ngt;
        }
        ax = rx; ay0 = ry0;
    };

    edge(q0.z, q0.w);                   // v0 -> v1
    #pragma unroll 4
    for (int jj = 1; jj < KV / 2; ++jj) {
        const float4 t = cv4[jj];
        edge(t.x, t.y);                 // -> v(2jj)
        edge(t.z, t.w);                 // -> v(2jj+1)
    }
    edge(q0.x, q0.y);                   // wrap v63 -> v0

    float pr[PPT];
    #pragma unroll
    for (int i = 0; i < PPT; ++i) {
        const float resize = __builtin_fabsf(wnf[i] + corr[i]);
        pr[i] = resize * __builtin_amdgcn_sqrtf(mindd[i]);
    }

    *(float4*)(out + bn * (MAP_SIZE * MAP_SIZE) + p0) =
        make_float4(pr[0], pr[1], pr[2], pr[3]);

    // block max -> plain store (NO global atomic)
    float m = fmaxf(fmaxf(pr[0], pr[1]), fmaxf(pr[2], pr[3]));
    #pragma unroll
    for (int off = 32; off > 0; off >>= 1)
        m = fmaxf(m, __shfl_xor(m, off));

    __shared__ float wmax[4];
    const int lane = threadIdx.x & 63;
    const int wid  = threadIdx.x >> 6;
    if (lane == 0) wmax[wid] = m;
    __syncthreads();
    if (threadIdx.x == 0)
        bmax[blockIdx.x] = fmaxf(fmaxf(wmax[0], wmax[1]), fmaxf(wmax[2], wmax[3]));
}

__global__ __launch_bounds__(256) void cdm_pass2(
    float4* __restrict__ out, const float* __restrict__ bmax, int nb, int n4)
{
    // every block re-reduces the block-max array (tiny, L2-resident)
    float m = 0.0f;
    for (int i = threadIdx.x; i < nb; i += 256) m = fmaxf(m, bmax[i]);
    #pragma unroll
    for (int off = 32; off > 0; off >>= 1)
        m = fmaxf(m, __shfl_xor(m, off));

    __shared__ float wm[4];
    if ((threadIdx.x & 63) == 0) wm[threadIdx.x >> 6] = m;
    __syncthreads();
    const float gm  = fmaxf(fmaxf(wm[0], wm[1]), fmaxf(wm[2], wm[3]));
    const float inv = 1.0f / gm;

    const int i = blockIdx.x * 256 + threadIdx.x;
    if (i < n4) {
        float4 v = out[i];
        v.x *= inv; v.y *= inv; v.z *= inv; v.w *= inv;
        out[i] = v;
    }
}

extern "C" void kernel_launch(void* const* d_in, const int* in_sizes, int n_in,
                              void* d_out, int out_size, void* d_ws, size_t ws_size,
                              hipStream_t stream) {
    const float* contour = (const float*)d_in[0];
    float* out  = (float*)d_out;
    float* bmax = (float*)d_ws;

    const int bn = in_sizes[0] / (KV * 2);            // 8
    const int npix = bn * MAP_SIZE * MAP_SIZE;        // 524288 == out_size

    const int blocksPerImg = (MAP_SIZE * MAP_SIZE) / (256 * PPT);  // 64
    const int nb = bn * blocksPerImg;                               // 512
    cdm_pass1<<<nb, 256, 0, stream>>>(contour, out, bmax);

    const int n4 = npix / 4;
    cdm_pass2<<<(n4 + 255) / 256, 256, 0, stream>>>((float4*)out, bmax, nb, n4);
}